// Round 30
// baseline (115.102 us; speedup 1.0000x reference)
//
#include <hip/hip_runtime.h>

#define T_LEN  4096
#define KS     16
#define NSEG   8           // T segments (512 output steps each)
#define SEG_CH 32          // output chunks per segment
#define WARM_CH 20         // 320 warm-up steps (validated R26/R28)

#define ALPHA_F 0.9048374180359595f
#define BETA_F  0.09516258196404048f
#define THETA_F 0.5f

// LDS-only barrier (R28-proven): drains LDS ops but not global traffic.
__device__ __forceinline__ void barrier_lds() {
  asm volatile("s_waitcnt lgkmcnt(0)\n\ts_barrier" ::: "memory");
}

// Full-wave (64-lane) max, result in ALL lanes. Verbatim from the passing
// R3-R29 kernels (manual s_nop hazard handling inside asm).
__device__ __forceinline__ float wave64_max_all(float v) {
  float m, t;
  asm("s_nop 1\n\t"
      "v_max_f32 %0, %2, %2 quad_perm:[1,0,3,2] row_mask:0xf bank_mask:0xf\n\t"
      "s_nop 1\n\t"
      "v_max_f32 %0, %0, %0 quad_perm:[2,3,0,1] row_mask:0xf bank_mask:0xf\n\t"
      "s_nop 1\n\t"
      "v_max_f32 %0, %0, %0 row_half_mirror row_mask:0xf bank_mask:0xf\n\t"
      "s_nop 1\n\t"
      "v_max_f32 %0, %0, %0 row_mirror row_mask:0xf bank_mask:0xf\n\t"
      "v_mov_b32 %1, %0\n\t"
      "s_nop 1\n\t"
      "v_permlane32_swap_b32 %1, %0\n\t"
      "s_nop 1\n\t"
      "v_max_f32 %0, %0, %1\n\t"
      "v_mov_b32 %1, %0\n\t"
      "s_nop 1\n\t"
      "v_permlane16_swap_b32 %1, %0\n\t"
      "s_nop 1\n\t"
      "v_max_f32 %0, %0, %1"
      : "=&v"(m), "=&v"(t)
      : "v"(v));
  return m;
}

__global__ __launch_bounds__(128, 5)
void convlif_wta_kernel(const float* __restrict__ x, const float* __restrict__ W,
                        float* __restrict__ out) {
  const int blk  = blockIdx.x;
  const int b    = blk >> 3;          // batch
  const int seg  = blk & (NSEG - 1);  // time segment
  const int wave = threadIdx.x >> 6;  // 0 = consumer (LIF), 1 = producer (conv)
  const int lane = threadIdx.x & 63;  // channel k

  const int cout0  = seg * SEG_CH;                                  // first output chunk
  const int cstart = (cout0 > WARM_CH) ? (cout0 - WARM_CH) : 0;     // warm-up start
  const int cend   = cout0 + SEG_CH;
  const int wpairs = (cout0 - cstart) >> 1;  // 10 (seg>0) or 0 (seg 0)
  const int npair  = (cend - cstart) >> 1;   // 26 (seg>0) or 16 (seg 0)

  // u handoff ring, TRANSPOSED: [slot][chunk-of-pair][i][lane].
  // For fixed i, lane l hits bank l&31 -> conflict-free writes AND reads,
  // no padding -> exactly 16,384 B -> 10 blocks/CU (vs 18,432 B -> 8).
  __shared__ float dbuf[2][2][16][64];

  const float4* xv4 = reinterpret_cast<const float4*>(x + (size_t)b * T_LEN);
  float* orow = out + ((size_t)(b * 64 + lane)) * T_LEN;   // this lane's channel row

  if (wave == 1) {
    // ================= producer: conv pairs into the LDS ring =============
    // (arithmetic verbatim R26/R28; only the LDS store layout changed)
    float w[KS];
    {
      const float4* w4 = reinterpret_cast<const float4*>(W + lane * KS);
      #pragma unroll
      for (int q = 0; q < 4; ++q) {
        float4 a = w4[q];
        w[4*q+0] = a.x; w[4*q+1] = a.y; w[4*q+2] = a.z; w[4*q+3] = a.w;
      }
    }

    for (int p = 0; p < npair; ++p) {
      #pragma unroll
      for (int ch = 0; ch < 2; ++ch) {
        const int c = cstart + 2 * p + ch;
        // conv for chunk c — verbatim summation order of all passing rounds
        float xf[32];
        if (c == 0) {
          #pragma unroll
          for (int m = 0; m < 16; ++m) xf[m] = 0.0f;
        } else {
          const int b4 = 4 * c - 4;
          #pragma unroll
          for (int q = 0; q < 4; ++q) {
            float4 a = xv4[b4 + q];
            xf[4*q+0] = a.x; xf[4*q+1] = a.y; xf[4*q+2] = a.z; xf[4*q+3] = a.w;
          }
        }
        #pragma unroll
        for (int q = 0; q < 4; ++q) {
          float4 a = xv4[4*c + q];
          xf[16+4*q+0] = a.x; xf[16+4*q+1] = a.y;
          xf[16+4*q+2] = a.z; xf[16+4*q+3] = a.w;
        }

        #pragma unroll
        for (int i = 0; i < 16; i += 2) {
          float acc0 = w[0] * xf[1 + i];
          #pragma unroll
          for (int j = 1; j < KS; ++j) acc0 = fmaf(w[j], xf[1 + i + j], acc0);
          float acc1 = w[0] * xf[2 + i];
          #pragma unroll
          for (int j = 1; j < KS; ++j) acc1 = fmaf(w[j], xf[2 + i + j], acc1);
          dbuf[p & 1][ch][i][lane]     = BETA_F * acc0;   // u[i]
          dbuf[p & 1][ch][i + 1][lane] = BETA_F * acc1;   // u[i+1]
        }
      }
      barrier_lds();     // pair p published; consumer reads it next interval
    }
    barrier_lds();       // final interval (consumer consumes last pair)
  } else {
    // ================= consumer: serial LIF + WTA over pairs ==============
    // Pipelined one pair behind the producer. Warm pairs run the lean body
    // (no sv/store — identical state arithmetic); output pairs the full body.
    float v = 0.0f;      // exact for seg 0 (no warm); speculative else

    barrier_lds();       // interval 0: producer fills pair 0

    // ---- warm pairs (lean: state only) ----
    for (int q = 0; q < wpairs; ++q) {
      const int slot = q & 1;
      #pragma unroll
      for (int ch = 0; ch < 2; ++ch) {
        float u[16];
        #pragma unroll
        for (int i = 0; i < 16; ++i) u[i] = dbuf[slot][ch][i][lane];
        #pragma unroll
        for (int i = 0; i < 16; ++i) {
          float vr = fmaf(ALPHA_F, v, u[i]);
          float vm = vr - THETA_F;
          unsigned long long sp = __ballot(vr >= THETA_F);
          bool c1 = (vr >= THETA_F);
          v = c1 ? vm : vr;
          if (__builtin_expect((sp & (sp - 1ull)) != 0ull, 0)) {
            float m = wave64_max_all(vr);
            unsigned long long eq = __ballot(vr == m);
            bool win = (lane == __builtin_ctzll(eq));
            v = win ? vm : vr;
          }
        }
      }
      barrier_lds();
    }

    // ---- output pairs (full body + store) ----
    for (int q = wpairs; q < npair; ++q) {
      const int slot = q & 1;
      #pragma unroll
      for (int ch = 0; ch < 2; ++ch) {
        const int c = cstart + 2 * q + ch;
        float u[16];
        #pragma unroll
        for (int i = 0; i < 16; ++i) u[i] = dbuf[slot][ch][i][lane];
        float sv[16];
        #pragma unroll
        for (int i = 0; i < 16; ++i) {
          float vr = fmaf(ALPHA_F, v, u[i]);
          float vm = vr - THETA_F;
          unsigned long long sp = __ballot(vr >= THETA_F);
          bool c1 = (vr >= THETA_F);
          sv[i] = c1 ? 1.0f : 0.0f;
          v     = c1 ? vm : vr;
          if (__builtin_expect((sp & (sp - 1ull)) != 0ull, 0)) {
            float m = wave64_max_all(vr);
            unsigned long long eq = __ballot(vr == m);
            bool win = (lane == __builtin_ctzll(eq));
            sv[i] = win ? 1.0f : 0.0f;
            v     = win ? vm : vr;
          }
        }
        float4* pp = reinterpret_cast<float4*>(orow + (size_t)c * 16);
        pp[0] = make_float4(sv[0],  sv[1],  sv[2],  sv[3]);
        pp[1] = make_float4(sv[4],  sv[5],  sv[6],  sv[7]);
        pp[2] = make_float4(sv[8],  sv[9],  sv[10], sv[11]);
        pp[3] = make_float4(sv[12], sv[13], sv[14], sv[15]);
      }
      barrier_lds();     // stores not drained (no cross-wave consumer)
    }
  }
}

extern "C" void kernel_launch(void* const* d_in, const int* in_sizes, int n_in,
                              void* d_out, int out_size, void* d_ws, size_t ws_size,
                              hipStream_t stream) {
  const float* x   = (const float*)d_in[0];
  const float* W   = (const float*)d_in[1];
  float*       out = (float*)d_out;
  convlif_wta_kernel<<<dim3(256 * NSEG), dim3(128), 0, stream>>>(x, W, out);
}

// Round 31
// 111.605 us; speedup vs baseline: 1.0313x; 1.0313x over previous
//
#include <hip/hip_runtime.h>

#define T_LEN  4096
#define KS     16
#define NSEG   8           // T segments (512 output steps each)
#define SEG_CH 32          // output chunks per segment
#define WARM_CH 20         // 320 warm-up steps (validated R26/R28)
#define USTRIDE 18         // u-row stride in dwords: 2-way bank aliasing, 8B-aligned

#define ALPHA_F 0.9048374180359595f
#define BETA_F  0.09516258196404048f
#define THETA_F 0.5f

// LDS-only barrier (R28-proven): drains LDS ops but not global traffic.
__device__ __forceinline__ void barrier_lds() {
  asm volatile("s_waitcnt lgkmcnt(0)\n\ts_barrier" ::: "memory");
}

// Full-wave (64-lane) max, result in ALL lanes. Verbatim from the passing
// R3-R30 kernels (manual s_nop hazard handling inside asm).
__device__ __forceinline__ float wave64_max_all(float v) {
  float m, t;
  asm("s_nop 1\n\t"
      "v_max_f32 %0, %2, %2 quad_perm:[1,0,3,2] row_mask:0xf bank_mask:0xf\n\t"
      "s_nop 1\n\t"
      "v_max_f32 %0, %0, %0 quad_perm:[2,3,0,1] row_mask:0xf bank_mask:0xf\n\t"
      "s_nop 1\n\t"
      "v_max_f32 %0, %0, %0 row_half_mirror row_mask:0xf bank_mask:0xf\n\t"
      "s_nop 1\n\t"
      "v_max_f32 %0, %0, %0 row_mirror row_mask:0xf bank_mask:0xf\n\t"
      "v_mov_b32 %1, %0\n\t"
      "s_nop 1\n\t"
      "v_permlane32_swap_b32 %1, %0\n\t"
      "s_nop 1\n\t"
      "v_max_f32 %0, %0, %1\n\t"
      "v_mov_b32 %1, %0\n\t"
      "s_nop 1\n\t"
      "v_permlane16_swap_b32 %1, %0\n\t"
      "s_nop 1\n\t"
      "v_max_f32 %0, %0, %1"
      : "=&v"(m), "=&v"(t)
      : "v"(v));
  return m;
}

__global__ __launch_bounds__(128, 4)
void convlif_wta_kernel(const float* __restrict__ x, const float* __restrict__ W,
                        float* __restrict__ out) {
  const int blk  = blockIdx.x;
  const int b    = blk >> 3;          // batch
  const int seg  = blk & (NSEG - 1);  // time segment
  const int wave = threadIdx.x >> 6;  // 0 = consumer (LIF), 1 = producer (conv)
  const int lane = threadIdx.x & 63;  // channel k

  const int cout0  = seg * SEG_CH;                                  // first output chunk
  const int cstart = (cout0 > WARM_CH) ? (cout0 - WARM_CH) : 0;     // warm-up start
  const int cend   = cout0 + SEG_CH;
  const int wpairs = (cout0 - cstart) >> 1;  // 10 (seg>0) or 0 (seg 0)
  const int npair  = (cend - cstart) >> 1;   // 26 (seg>0) or 16 (seg 0)

  // u handoff ring: [slot][chunk-of-pair][lane][i]; stride 18 dwords ->
  // float2 8B-aligned, 2-way bank aliasing (free). 18 KB/block -> 8 blocks/CU.
  __shared__ float dbuf[2][2][64][USTRIDE];

  const float4* xv4 = reinterpret_cast<const float4*>(x + (size_t)b * T_LEN);
  float* orow = out + ((size_t)(b * 64 + lane)) * T_LEN;   // this lane's channel row

  if (wave == 1) {
    // ================= producer: conv pairs into the LDS ring =============
    // (verbatim R28; priority stays 0 — fills the consumer's stall slots)
    float w[KS];
    {
      const float4* w4 = reinterpret_cast<const float4*>(W + lane * KS);
      #pragma unroll
      for (int q = 0; q < 4; ++q) {
        float4 a = w4[q];
        w[4*q+0] = a.x; w[4*q+1] = a.y; w[4*q+2] = a.z; w[4*q+3] = a.w;
      }
    }

    for (int p = 0; p < npair; ++p) {
      #pragma unroll
      for (int ch = 0; ch < 2; ++ch) {
        const int c = cstart + 2 * p + ch;
        // conv for chunk c — verbatim summation order of all passing rounds
        float xf[32];
        if (c == 0) {
          #pragma unroll
          for (int m = 0; m < 16; ++m) xf[m] = 0.0f;
        } else {
          const int b4 = 4 * c - 4;
          #pragma unroll
          for (int q = 0; q < 4; ++q) {
            float4 a = xv4[b4 + q];
            xf[4*q+0] = a.x; xf[4*q+1] = a.y; xf[4*q+2] = a.z; xf[4*q+3] = a.w;
          }
        }
        #pragma unroll
        for (int q = 0; q < 4; ++q) {
          float4 a = xv4[4*c + q];
          xf[16+4*q+0] = a.x; xf[16+4*q+1] = a.y;
          xf[16+4*q+2] = a.z; xf[16+4*q+3] = a.w;
        }

        float* ur = &dbuf[p & 1][ch][lane][0];
        #pragma unroll
        for (int i = 0; i < 16; i += 2) {
          float acc0 = w[0] * xf[1 + i];
          #pragma unroll
          for (int j = 1; j < KS; ++j) acc0 = fmaf(w[j], xf[1 + i + j], acc0);
          float acc1 = w[0] * xf[2 + i];
          #pragma unroll
          for (int j = 1; j < KS; ++j) acc1 = fmaf(w[j], xf[2 + i + j], acc1);
          *reinterpret_cast<float2*>(ur + i) =
              make_float2(BETA_F * acc0, BETA_F * acc1);   // u[i], u[i+1]
        }
      }
      barrier_lds();     // pair p published; consumer reads it next interval
    }
    barrier_lds();       // final interval (consumer consumes last pair)
  } else {
    // ================= consumer: serial LIF + WTA over pairs ==============
    // The serial chain is the block's critical path: raise this wave's issue
    // priority so chain-dependent instructions win SIMD arbitration against
    // the co-resident producer waves (which have abundant independent work).
    __builtin_amdgcn_s_setprio(1);

    float v = 0.0f;      // exact for seg 0 (no warm); speculative else
    barrier_lds();       // interval 0: producer fills pair 0

    // ---- warm pairs (lean: state only) ----
    for (int q = 0; q < wpairs; ++q) {
      const int slot = q & 1;
      #pragma unroll
      for (int ch = 0; ch < 2; ++ch) {
        float u[16];
        {
          const float* ur = &dbuf[slot][ch][lane][0];
          #pragma unroll
          for (int i = 0; i < 16; i += 2) {
            float2 t2 = *reinterpret_cast<const float2*>(ur + i);
            u[i] = t2.x; u[i + 1] = t2.y;
          }
        }
        #pragma unroll
        for (int i = 0; i < 16; ++i) {
          float vr = fmaf(ALPHA_F, v, u[i]);
          float vm = vr - THETA_F;
          unsigned long long sp = __ballot(vr >= THETA_F);
          bool c1 = (vr >= THETA_F);
          v = c1 ? vm : vr;
          if (__builtin_expect((sp & (sp - 1ull)) != 0ull, 0)) {
            float m = wave64_max_all(vr);
            unsigned long long eq = __ballot(vr == m);
            bool win = (lane == __builtin_ctzll(eq));
            v = win ? vm : vr;
          }
        }
      }
      barrier_lds();
    }

    // ---- output pairs (full body + store) ----
    for (int q = wpairs; q < npair; ++q) {
      const int slot = q & 1;
      #pragma unroll
      for (int ch = 0; ch < 2; ++ch) {
        const int c = cstart + 2 * q + ch;
        float u[16];
        {
          const float* ur = &dbuf[slot][ch][lane][0];
          #pragma unroll
          for (int i = 0; i < 16; i += 2) {
            float2 t2 = *reinterpret_cast<const float2*>(ur + i);
            u[i] = t2.x; u[i + 1] = t2.y;
          }
        }
        float sv[16];
        #pragma unroll
        for (int i = 0; i < 16; ++i) {
          float vr = fmaf(ALPHA_F, v, u[i]);
          float vm = vr - THETA_F;
          unsigned long long sp = __ballot(vr >= THETA_F);
          bool c1 = (vr >= THETA_F);
          sv[i] = c1 ? 1.0f : 0.0f;
          v     = c1 ? vm : vr;
          if (__builtin_expect((sp & (sp - 1ull)) != 0ull, 0)) {
            float m = wave64_max_all(vr);
            unsigned long long eq = __ballot(vr == m);
            bool win = (lane == __builtin_ctzll(eq));
            sv[i] = win ? 1.0f : 0.0f;
            v     = win ? vm : vr;
          }
        }
        float4* pp = reinterpret_cast<float4*>(orow + (size_t)c * 16);
        pp[0] = make_float4(sv[0],  sv[1],  sv[2],  sv[3]);
        pp[1] = make_float4(sv[4],  sv[5],  sv[6],  sv[7]);
        pp[2] = make_float4(sv[8],  sv[9],  sv[10], sv[11]);
        pp[3] = make_float4(sv[12], sv[13], sv[14], sv[15]);
      }
      barrier_lds();     // stores not drained (no cross-wave consumer)
    }
    __builtin_amdgcn_s_setprio(0);
  }
}

extern "C" void kernel_launch(void* const* d_in, const int* in_sizes, int n_in,
                              void* d_out, int out_size, void* d_ws, size_t ws_size,
                              hipStream_t stream) {
  const float* x   = (const float*)d_in[0];
  const float* W   = (const float*)d_in[1];
  float*       out = (float*)d_out;
  convlif_wta_kernel<<<dim3(256 * NSEG), dim3(128), 0, stream>>>(x, W, out);
}

// Round 32
// 105.649 us; speedup vs baseline: 1.0895x; 1.0564x over previous
//
#include <hip/hip_runtime.h>

#define T_LEN  4096
#define KS     16
#define NSEG   8           // T segments (512 output steps each)
#define SEG_CH 32          // output chunks per segment
#define WARM_CH 20         // 320 warm-up steps (validated R26/R28)
#define USTRIDE 18         // u-row stride in dwords: 2-way bank aliasing, 8B-aligned

#define ALPHA_F 0.9048374180359595f
#define BETA_F  0.09516258196404048f
#define THETA_F 0.5f

// LDS-only barrier: drains LDS ops (lgkmcnt) but NOT global traffic (vmcnt).
// The only cross-wave dependency in this kernel is the dbuf LDS ring.
__device__ __forceinline__ void barrier_lds() {
  asm volatile("s_waitcnt lgkmcnt(0)\n\ts_barrier" ::: "memory");
}

// Full-wave (64-lane) max, result in ALL lanes. Verbatim from the passing
// R3-R31 kernels (manual s_nop hazard handling inside asm).
__device__ __forceinline__ float wave64_max_all(float v) {
  float m, t;
  asm("s_nop 1\n\t"
      "v_max_f32 %0, %2, %2 quad_perm:[1,0,3,2] row_mask:0xf bank_mask:0xf\n\t"
      "s_nop 1\n\t"
      "v_max_f32 %0, %0, %0 quad_perm:[2,3,0,1] row_mask:0xf bank_mask:0xf\n\t"
      "s_nop 1\n\t"
      "v_max_f32 %0, %0, %0 row_half_mirror row_mask:0xf bank_mask:0xf\n\t"
      "s_nop 1\n\t"
      "v_max_f32 %0, %0, %0 row_mirror row_mask:0xf bank_mask:0xf\n\t"
      "v_mov_b32 %1, %0\n\t"
      "s_nop 1\n\t"
      "v_permlane32_swap_b32 %1, %0\n\t"
      "s_nop 1\n\t"
      "v_max_f32 %0, %0, %1\n\t"
      "v_mov_b32 %1, %0\n\t"
      "s_nop 1\n\t"
      "v_permlane16_swap_b32 %1, %0\n\t"
      "s_nop 1\n\t"
      "v_max_f32 %0, %0, %1"
      : "=&v"(m), "=&v"(t)
      : "v"(v));
  return m;
}

__global__ __launch_bounds__(128, 4)
void convlif_wta_kernel(const float* __restrict__ x, const float* __restrict__ W,
                        float* __restrict__ out) {
  const int blk  = blockIdx.x;
  const int b    = blk >> 3;          // batch
  const int seg  = blk & (NSEG - 1);  // time segment
  const int wave = threadIdx.x >> 6;  // 0 = consumer (LIF), 1 = producer (conv)
  const int lane = threadIdx.x & 63;  // channel k

  const int cout0  = seg * SEG_CH;                                  // first output chunk
  const int cstart = (cout0 > WARM_CH) ? (cout0 - WARM_CH) : 0;     // warm-up start
  const int cend   = cout0 + SEG_CH;
  const int wpairs = (cout0 - cstart) >> 1;  // 10 (seg>0) or 0 (seg 0)
  const int npair  = (cend - cstart) >> 1;   // 26 (seg>0) or 16 (seg 0)

  // u handoff ring: [slot][chunk-of-pair][lane][i]; stride 18 dwords ->
  // float2 8B-aligned, 2-way bank aliasing (free). 18 KB/block -> 8 blocks/CU.
  __shared__ float dbuf[2][2][64][USTRIDE];

  const float4* xv4 = reinterpret_cast<const float4*>(x + (size_t)b * T_LEN);
  float* orow = out + ((size_t)(b * 64 + lane)) * T_LEN;   // this lane's channel row

  if (wave == 1) {
    // ================= producer: conv pairs into the LDS ring =============
    float w[KS];
    {
      const float4* w4 = reinterpret_cast<const float4*>(W + lane * KS);
      #pragma unroll
      for (int q = 0; q < 4; ++q) {
        float4 a = w4[q];
        w[4*q+0] = a.x; w[4*q+1] = a.y; w[4*q+2] = a.z; w[4*q+3] = a.w;
      }
    }

    for (int p = 0; p < npair; ++p) {
      #pragma unroll
      for (int ch = 0; ch < 2; ++ch) {
        const int c = cstart + 2 * p + ch;
        // conv for chunk c — verbatim summation order of all passing rounds
        float xf[32];
        if (c == 0) {
          #pragma unroll
          for (int m = 0; m < 16; ++m) xf[m] = 0.0f;
        } else {
          const int b4 = 4 * c - 4;
          #pragma unroll
          for (int q = 0; q < 4; ++q) {
            float4 a = xv4[b4 + q];
            xf[4*q+0] = a.x; xf[4*q+1] = a.y; xf[4*q+2] = a.z; xf[4*q+3] = a.w;
          }
        }
        #pragma unroll
        for (int q = 0; q < 4; ++q) {
          float4 a = xv4[4*c + q];
          xf[16+4*q+0] = a.x; xf[16+4*q+1] = a.y;
          xf[16+4*q+2] = a.z; xf[16+4*q+3] = a.w;
        }

        float* ur = &dbuf[p & 1][ch][lane][0];
        #pragma unroll
        for (int i = 0; i < 16; i += 2) {
          float acc0 = w[0] * xf[1 + i];
          #pragma unroll
          for (int j = 1; j < KS; ++j) acc0 = fmaf(w[j], xf[1 + i + j], acc0);
          float acc1 = w[0] * xf[2 + i];
          #pragma unroll
          for (int j = 1; j < KS; ++j) acc1 = fmaf(w[j], xf[2 + i + j], acc1);
          *reinterpret_cast<float2*>(ur + i) =
              make_float2(BETA_F * acc0, BETA_F * acc1);   // u[i], u[i+1]
        }
      }
      barrier_lds();     // pair p published; consumer reads it next interval
    }
    barrier_lds();       // final interval (consumer consumes last pair)
  } else {
    // ================= consumer: serial LIF + WTA over pairs ==============
    // Pipelined one pair behind the producer. Warm pairs run the lean body
    // (no sv/store — identical state arithmetic); output pairs the full body.
    float v = 0.0f;      // exact for seg 0 (no warm); speculative else

    barrier_lds();       // interval 0: producer fills pair 0

    // ---- warm pairs (lean: state only) ----
    for (int q = 0; q < wpairs; ++q) {
      const int slot = q & 1;
      #pragma unroll
      for (int ch = 0; ch < 2; ++ch) {
        float u[16];
        {
          const float* ur = &dbuf[slot][ch][lane][0];
          #pragma unroll
          for (int i = 0; i < 16; i += 2) {
            float2 t2 = *reinterpret_cast<const float2*>(ur + i);
            u[i] = t2.x; u[i + 1] = t2.y;
          }
        }
        #pragma unroll
        for (int i = 0; i < 16; ++i) {
          float vr = fmaf(ALPHA_F, v, u[i]);
          float vm = vr - THETA_F;
          unsigned long long sp = __ballot(vr >= THETA_F);
          bool c1 = (vr >= THETA_F);
          v = c1 ? vm : vr;
          if (__builtin_expect((sp & (sp - 1ull)) != 0ull, 0)) {
            float m = wave64_max_all(vr);
            unsigned long long eq = __ballot(vr == m);
            bool win = (lane == __builtin_ctzll(eq));
            v = win ? vm : vr;
          }
        }
      }
      barrier_lds();
    }

    // ---- output pairs (full body + store) ----
    for (int q = wpairs; q < npair; ++q) {
      const int slot = q & 1;
      #pragma unroll
      for (int ch = 0; ch < 2; ++ch) {
        const int c = cstart + 2 * q + ch;
        float u[16];
        {
          const float* ur = &dbuf[slot][ch][lane][0];
          #pragma unroll
          for (int i = 0; i < 16; i += 2) {
            float2 t2 = *reinterpret_cast<const float2*>(ur + i);
            u[i] = t2.x; u[i + 1] = t2.y;
          }
        }
        float sv[16];
        #pragma unroll
        for (int i = 0; i < 16; ++i) {
          float vr = fmaf(ALPHA_F, v, u[i]);
          float vm = vr - THETA_F;
          unsigned long long sp = __ballot(vr >= THETA_F);
          bool c1 = (vr >= THETA_F);
          sv[i] = c1 ? 1.0f : 0.0f;
          v     = c1 ? vm : vr;
          if (__builtin_expect((sp & (sp - 1ull)) != 0ull, 0)) {
            float m = wave64_max_all(vr);
            unsigned long long eq = __ballot(vr == m);
            bool win = (lane == __builtin_ctzll(eq));
            sv[i] = win ? 1.0f : 0.0f;
            v     = win ? vm : vr;
          }
        }
        float4* pp = reinterpret_cast<float4*>(orow + (size_t)c * 16);
        pp[0] = make_float4(sv[0],  sv[1],  sv[2],  sv[3]);
        pp[1] = make_float4(sv[4],  sv[5],  sv[6],  sv[7]);
        pp[2] = make_float4(sv[8],  sv[9],  sv[10], sv[11]);
        pp[3] = make_float4(sv[12], sv[13], sv[14], sv[15]);
      }
      barrier_lds();     // stores not drained (no cross-wave consumer)
    }
  }
}

extern "C" void kernel_launch(void* const* d_in, const int* in_sizes, int n_in,
                              void* d_out, int out_size, void* d_ws, size_t ws_size,
                              hipStream_t stream) {
  const float* x   = (const float*)d_in[0];
  const float* W   = (const float*)d_in[1];
  float*       out = (float*)d_out;
  convlif_wta_kernel<<<dim3(256 * NSEG), dim3(128), 0, stream>>>(x, W, out);
}